// Round 1
// baseline (15033.275 us; speedup 1.0000x reference)
//
#include <hip/hip_runtime.h>
#include <stdint.h>

#define TT 4096
#define INW 1024
#define HW 1024
#define OUTW 512
#define CH 2048  // HW+INW

// ws layout:
//   [0, 16KB)           : hpair[2][1024]  (uint64: epoch<<32 | float_bits)
//   [16KB, 16KB+16MB)   : h_all float[TT*HW]

__device__ __forceinline__ uint64_t pack_pair(float v, uint32_t ep) {
    return ((uint64_t)ep << 32) | (uint64_t)__float_as_uint(v);
}

__global__ void lstm_init_kernel(uint64_t* __restrict__ hpair) {
    int j = blockIdx.x * blockDim.x + threadIdx.x;
    if (j < HW) {
        hpair[j]      = pack_pair(0.0f, 0u);          // buf0: h_0 = 0, epoch 0
        hpair[HW + j] = pack_pair(0.0f, 0x80000000u); // buf1: never-matching epoch
    }
}

// 256 blocks x 256 threads. Block b owns hidden units 4b..4b+3.
// Wave w owns unit gu = 4b+w (all four gates f,i,c~,o).
// Lane l covers concat columns {l + 64k : k=0..31}; k<16 -> h part, k>=16 -> x part.
__global__ __launch_bounds__(256, 2) void lstm_seq_kernel(
    const float* __restrict__ x,
    const float* __restrict__ wf, const float* __restrict__ bf,
    const float* __restrict__ wi, const float* __restrict__ bi,
    const float* __restrict__ wc, const float* __restrict__ bc,
    const float* __restrict__ wo, const float* __restrict__ bo,
    uint64_t* __restrict__ hpair, float* __restrict__ h_all,
    float* __restrict__ out)
{
    __shared__ float hsh[HW];  // 4KB: h_t shared within block

    const int tid  = threadIdx.x;
    const int lane = tid & 63;
    const int w    = tid >> 6;            // wave 0..3
    const int b    = blockIdx.x;          // 0..255
    const int gu   = b * 4 + w;           // global hidden unit owned by this wave

    // ---- one-time: load weights into registers (coalesced: lane-stride 4B) ----
    float wreg[128];  // wreg[j*32+k] = W_j[gu*2048 + lane + 64k]
    {
        const float* wptr[4] = {wf, wi, wc, wo};
#pragma unroll
        for (int j = 0; j < 4; ++j) {
            const float* base = wptr[j] + (size_t)gu * CH + lane;
#pragma unroll
            for (int k = 0; k < 32; ++k) {
                wreg[j * 32 + k] = base[(size_t)k * 64];
            }
        }
    }
    const float bias0 = bf[gu];
    const float bias1 = bi[gu];
    const float bias2 = bc[gu];
    const float bias3 = bo[gu];

    float c = 0.0f;       // cell state (meaningful on lane 0)
    float h_last = 0.0f;  // last hidden (meaningful on lane 0)

    for (int t = 0; t < TT; ++t) {
        float acc0 = 0.0f, acc1 = 0.0f, acc2 = 0.0f, acc3 = 0.0f;

        // ---- x part (independent of recurrence; overlaps the h wait) ----
        const float* xt = x + (size_t)t * INW + lane;
#pragma unroll
        for (int k = 0; k < 16; ++k) {
            float xv = xt[(size_t)k * 64];
            acc0 = fmaf(wreg[0 * 32 + 16 + k], xv, acc0);
            acc1 = fmaf(wreg[1 * 32 + 16 + k], xv, acc1);
            acc2 = fmaf(wreg[2 * 32 + 16 + k], xv, acc2);
            acc3 = fmaf(wreg[3 * 32 + 16 + k], xv, acc3);
        }

        // ---- wave 0 polls the fused (epoch,value) pairs for h_t ----
        const uint64_t* hp = hpair + (size_t)(t & 1) * HW;
        if (w == 0) {
            float hv[16];
            bool ok;
            do {
                uint64_t pv[16];
#pragma unroll
                for (int k = 0; k < 16; ++k)
                    pv[k] = __hip_atomic_load(&hp[lane + 64 * k],
                                              __ATOMIC_RELAXED, __HIP_MEMORY_SCOPE_AGENT);
                ok = true;
#pragma unroll
                for (int k = 0; k < 16; ++k)
                    ok &= ((uint32_t)(pv[k] >> 32) == (uint32_t)t);
#pragma unroll
                for (int k = 0; k < 16; ++k)
                    hv[k] = __uint_as_float((uint32_t)pv[k]);
            } while (!__all(ok));
#pragma unroll
            for (int k = 0; k < 16; ++k)
                hsh[lane + 64 * k] = hv[k];  // bank-conflict-free (stride 64)
        }
        __syncthreads();

        // ---- h part ----
#pragma unroll
        for (int k = 0; k < 16; ++k) {
            float hv = hsh[lane + 64 * k];
            acc0 = fmaf(wreg[0 * 32 + k], hv, acc0);
            acc1 = fmaf(wreg[1 * 32 + k], hv, acc1);
            acc2 = fmaf(wreg[2 * 32 + k], hv, acc2);
            acc3 = fmaf(wreg[3 * 32 + k], hv, acc3);
        }
        // NOTE: no second __syncthreads needed: wave0 can only rewrite hsh (next
        // iter) after observing ALL blocks' h_{t+1}, which requires this block's
        // waves 1..3 to have published, i.e. to be past their hsh reads.

        // ---- 64-lane reduction per gate ----
#pragma unroll
        for (int s = 32; s > 0; s >>= 1) {
            acc0 += __shfl_xor(acc0, s, 64);
            acc1 += __shfl_xor(acc1, s, 64);
            acc2 += __shfl_xor(acc2, s, 64);
            acc3 += __shfl_xor(acc3, s, 64);
        }

        if (lane == 0) {
            float f  = 1.0f / (1.0f + __expf(-(acc0 + bias0)));
            float ii = 1.0f / (1.0f + __expf(-(acc1 + bias1)));
            float g  = tanhf(acc2 + bias2);
            float o  = 1.0f / (1.0f + __expf(-(acc3 + bias3)));
            c = fmaf(f, c, ii * g);
            float hn = o * tanhf(c);
            h_last = hn;
            h_all[(size_t)t * HW + gu] = hn;  // for the ys GEMM (read next kernel)
            __hip_atomic_store(&hpair[(size_t)((t + 1) & 1) * HW + gu],
                               pack_pair(hn, (uint32_t)(t + 1)),
                               __ATOMIC_RELAXED, __HIP_MEMORY_SCOPE_AGENT);
        }
    }

    // ---- final h, c outputs ----
    if (lane == 0) {
        out[(size_t)TT * OUTW + gu]      = h_last;
        out[(size_t)TT * OUTW + HW + gu] = c;
    }
}

// ys[t][o] = sum_k h_all[t][k] * why[o][k] + by[o]
// grid (TT/64, OUTW/64) = (64, 8); block 256; 64x64 tile, 4x4 per thread.
__global__ __launch_bounds__(256) void lstm_ygemm_kernel(
    const float* __restrict__ hall, const float* __restrict__ why,
    const float* __restrict__ by, float* __restrict__ ys)
{
    __shared__ float hs[64][17];
    __shared__ float wsm[64][17];
    const int t0 = blockIdx.x * 64, o0 = blockIdx.y * 64;
    const int tid = threadIdx.x;
    const int tx = tid & 15, ty = tid >> 4;

    float acc[4][4] = {};
    const int r = tid >> 2;            // 0..63
    const int cc = (tid & 3) * 4;      // 0,4,8,12

    for (int kk = 0; kk < HW; kk += 16) {
        float4 hv = *(const float4*)(hall + (size_t)(t0 + r) * HW + kk + cc);
        hs[r][cc + 0] = hv.x; hs[r][cc + 1] = hv.y;
        hs[r][cc + 2] = hv.z; hs[r][cc + 3] = hv.w;
        float4 wv = *(const float4*)(why + (size_t)(o0 + r) * HW + kk + cc);
        wsm[r][cc + 0] = wv.x; wsm[r][cc + 1] = wv.y;
        wsm[r][cc + 2] = wv.z; wsm[r][cc + 3] = wv.w;
        __syncthreads();
#pragma unroll
        for (int k = 0; k < 16; ++k) {
            float ha[4], wa[4];
#pragma unroll
            for (int i = 0; i < 4; ++i) ha[i] = hs[ty * 4 + i][k];
#pragma unroll
            for (int j = 0; j < 4; ++j) wa[j] = wsm[tx * 4 + j][k];
#pragma unroll
            for (int i = 0; i < 4; ++i)
#pragma unroll
                for (int j = 0; j < 4; ++j)
                    acc[i][j] = fmaf(ha[i], wa[j], acc[i][j]);
        }
        __syncthreads();
    }
#pragma unroll
    for (int i = 0; i < 4; ++i) {
#pragma unroll
        for (int j = 0; j < 4; ++j) {
            int oo = o0 + tx * 4 + j;
            ys[(size_t)(t0 + ty * 4 + i) * OUTW + oo] = acc[i][j] + by[oo];
        }
    }
}

extern "C" void kernel_launch(void* const* d_in, const int* in_sizes, int n_in,
                              void* d_out, int out_size, void* d_ws, size_t ws_size,
                              hipStream_t stream) {
    const float* x   = (const float*)d_in[0];
    const float* wf  = (const float*)d_in[1];
    const float* bf  = (const float*)d_in[2];
    const float* wi  = (const float*)d_in[3];
    const float* bi  = (const float*)d_in[4];
    const float* wc  = (const float*)d_in[5];
    const float* bc  = (const float*)d_in[6];
    const float* wo  = (const float*)d_in[7];
    const float* bo  = (const float*)d_in[8];
    const float* why = (const float*)d_in[9];
    const float* by  = (const float*)d_in[10];
    float* out = (float*)d_out;

    uint64_t* hpair = (uint64_t*)d_ws;
    float* h_all = (float*)((char*)d_ws + (size_t)2 * HW * sizeof(uint64_t));

    lstm_init_kernel<<<dim3(4), dim3(256), 0, stream>>>(hpair);
    lstm_seq_kernel<<<dim3(256), dim3(256), 0, stream>>>(
        x, wf, bf, wi, bi, wc, bc, wo, bo, hpair, h_all, out);
    lstm_ygemm_kernel<<<dim3(64, 8), dim3(256), 0, stream>>>(h_all, why, by, out);
}

// Round 2
// 13863.818 us; speedup vs baseline: 1.0844x; 1.0844x over previous
//
#include <hip/hip_runtime.h>
#include <stdint.h>

#define TT 4096
#define INW 1024
#define HW 1024
#define OUTW 512
#define CH 2048  // HW+INW

// ws layout:
//   [0, 16KB)           : hpair[2][1024]  (uint64: epoch<<32 | float_bits)
//   [16KB, 16KB+16MB)   : h_all float[TT*HW]

__device__ __forceinline__ uint64_t pack_pair(float v, uint32_t ep) {
    return ((uint64_t)ep << 32) | (uint64_t)__float_as_uint(v);
}

__device__ __forceinline__ float sigmoid_fast(float z) {
    return 1.0f / (1.0f + __expf(-z));
}
__device__ __forceinline__ float tanh_fast(float z) {
    // exact at saturation: z>>0 -> 1 - 2/inf = 1 ; z<<0 -> 1 - 2/1+0 .. -> -1
    return 1.0f - 2.0f / (1.0f + __expf(2.0f * z));
}

__global__ void lstm_init_kernel(uint64_t* __restrict__ hpair) {
    int j = blockIdx.x * blockDim.x + threadIdx.x;
    if (j < HW) {
        hpair[j]      = pack_pair(0.0f, 0u);          // buf0: h_0 = 0, epoch 0
        hpair[HW + j] = pack_pair(0.0f, 0x80000000u); // buf1: never-matching epoch
    }
}

// 256 blocks x 256 threads. Block b owns hidden units 4b..4b+3.
// Wave w owns unit gu = 4b+w (all four gates f,i,c~,o).
// Lane l covers concat columns {l + 64k : k=0..31}; k<16 -> h part, k>=16 -> x part.
__global__ __launch_bounds__(256, 2) void lstm_seq_kernel(
    const float* __restrict__ x,
    const float* __restrict__ wf, const float* __restrict__ bf,
    const float* __restrict__ wi, const float* __restrict__ bi,
    const float* __restrict__ wc, const float* __restrict__ bc,
    const float* __restrict__ wo, const float* __restrict__ bo,
    uint64_t* __restrict__ hpair, float* __restrict__ h_all,
    float* __restrict__ out)
{
    __shared__ float hsh[HW];  // 4KB: h_t shared within block

    const int tid  = threadIdx.x;
    const int lane = tid & 63;
    const int w    = tid >> 6;            // wave 0..3
    const int b    = blockIdx.x;          // 0..255
    const int gu   = b * 4 + w;           // global hidden unit owned by this wave

    // ---- one-time: load weights into registers (coalesced: lane-stride 4B) ----
    float wreg[128];  // wreg[j*32+k] = W_j[gu*2048 + lane + 64k]
    {
        const float* wptr[4] = {wf, wi, wc, wo};
#pragma unroll
        for (int j = 0; j < 4; ++j) {
            const float* base = wptr[j] + (size_t)gu * CH + lane;
#pragma unroll
            for (int k = 0; k < 32; ++k) {
                wreg[j * 32 + k] = base[(size_t)k * 64];
            }
        }
    }
    const float bias0 = bf[gu];
    const float bias1 = bi[gu];
    const float bias2 = bc[gu];
    const float bias3 = bo[gu];

    float c = 0.0f;       // cell state (meaningful on lane 0)
    float h_last = 0.0f;  // last hidden (meaningful on lane 0)

    for (int t = 0; t < TT; ++t) {
        float acc0 = 0.0f, acc1 = 0.0f, acc2 = 0.0f, acc3 = 0.0f;

        // ---- x part (independent of recurrence; overlaps the h wait) ----
        const float* xt = x + (size_t)t * INW + lane;
#pragma unroll
        for (int k = 0; k < 16; ++k) {
            float xv = xt[(size_t)k * 64];
            acc0 = fmaf(wreg[0 * 32 + 16 + k], xv, acc0);
            acc1 = fmaf(wreg[1 * 32 + 16 + k], xv, acc1);
            acc2 = fmaf(wreg[2 * 32 + 16 + k], xv, acc2);
            acc3 = fmaf(wreg[3 * 32 + 16 + k], xv, acc3);
        }

        // ---- wave 0 polls the fused (epoch,value) pairs for h_t ----
        // SYSTEM-scope loads: sc0 sc1 -> bypass L1+L2, read the device
        // coherence point directly (no stale-L2/invalidation latency).
        const uint64_t* hp = hpair + (size_t)(t & 1) * HW;
        if (w == 0) {
            float hv[16];
            bool ok;
            do {
                uint64_t pv[16];
#pragma unroll
                for (int k = 0; k < 16; ++k)
                    pv[k] = __hip_atomic_load(&hp[lane + 64 * k],
                                              __ATOMIC_RELAXED, __HIP_MEMORY_SCOPE_SYSTEM);
                ok = true;
#pragma unroll
                for (int k = 0; k < 16; ++k)
                    ok &= ((uint32_t)(pv[k] >> 32) == (uint32_t)t);
#pragma unroll
                for (int k = 0; k < 16; ++k)
                    hv[k] = __uint_as_float((uint32_t)pv[k]);
            } while (!__all(ok));
#pragma unroll
            for (int k = 0; k < 16; ++k)
                hsh[lane + 64 * k] = hv[k];  // bank-conflict-free (stride 64)
        }
        __syncthreads();

        // ---- h part ----
#pragma unroll
        for (int k = 0; k < 16; ++k) {
            float hv = hsh[lane + 64 * k];
            acc0 = fmaf(wreg[0 * 32 + k], hv, acc0);
            acc1 = fmaf(wreg[1 * 32 + k], hv, acc1);
            acc2 = fmaf(wreg[2 * 32 + k], hv, acc2);
            acc3 = fmaf(wreg[3 * 32 + k], hv, acc3);
        }
        // NOTE: no second __syncthreads needed: wave0 can only rewrite hsh (next
        // iter) after observing ALL blocks' h_{t+1}, which requires this block's
        // waves 1..3 to have published, i.e. to be past their hsh reads.

        // ---- 64-lane reduction per gate ----
#pragma unroll
        for (int s = 32; s > 0; s >>= 1) {
            acc0 += __shfl_xor(acc0, s, 64);
            acc1 += __shfl_xor(acc1, s, 64);
            acc2 += __shfl_xor(acc2, s, 64);
            acc3 += __shfl_xor(acc3, s, 64);
        }

        if (lane == 0) {
            float f  = sigmoid_fast(acc0 + bias0);
            float ii = sigmoid_fast(acc1 + bias1);
            float g  = tanh_fast(acc2 + bias2);
            float o  = sigmoid_fast(acc3 + bias3);
            c = fmaf(f, c, ii * g);
            float hn = o * tanh_fast(c);
            // Publish FIRST (memory-side RMW: lands at the coherence point
            // immediately, never lingers dirty in this XCD's L2).
            (void)__hip_atomic_exchange(
                &hpair[(size_t)((t + 1) & 1) * HW + gu],
                pack_pair(hn, (uint32_t)(t + 1)),
                __ATOMIC_RELAXED, __HIP_MEMORY_SCOPE_AGENT);
            h_last = hn;
            h_all[(size_t)t * HW + gu] = hn;  // for the ys GEMM (read next kernel)
        }
    }

    // ---- final h, c outputs ----
    if (lane == 0) {
        out[(size_t)TT * OUTW + gu]      = h_last;
        out[(size_t)TT * OUTW + HW + gu] = c;
    }
}

// ys[t][o] = sum_k h_all[t][k] * why[o][k] + by[o]
// grid (TT/64, OUTW/64) = (64, 8); block 256; 64x64 tile, 4x4 per thread.
__global__ __launch_bounds__(256) void lstm_ygemm_kernel(
    const float* __restrict__ hall, const float* __restrict__ why,
    const float* __restrict__ by, float* __restrict__ ys)
{
    __shared__ float hs[64][17];
    __shared__ float wsm[64][17];
    const int t0 = blockIdx.x * 64, o0 = blockIdx.y * 64;
    const int tid = threadIdx.x;
    const int tx = tid & 15, ty = tid >> 4;

    float acc[4][4] = {};
    const int r = tid >> 2;            // 0..63
    const int cc = (tid & 3) * 4;      // 0,4,8,12

    for (int kk = 0; kk < HW; kk += 16) {
        float4 hv = *(const float4*)(hall + (size_t)(t0 + r) * HW + kk + cc);
        hs[r][cc + 0] = hv.x; hs[r][cc + 1] = hv.y;
        hs[r][cc + 2] = hv.z; hs[r][cc + 3] = hv.w;
        float4 wv = *(const float4*)(why + (size_t)(o0 + r) * HW + kk + cc);
        wsm[r][cc + 0] = wv.x; wsm[r][cc + 1] = wv.y;
        wsm[r][cc + 2] = wv.z; wsm[r][cc + 3] = wv.w;
        __syncthreads();
#pragma unroll
        for (int k = 0; k < 16; ++k) {
            float ha[4], wa[4];
#pragma unroll
            for (int i = 0; i < 4; ++i) ha[i] = hs[ty * 4 + i][k];
#pragma unroll
            for (int j = 0; j < 4; ++j) wa[j] = wsm[tx * 4 + j][k];
#pragma unroll
            for (int i = 0; i < 4; ++i)
#pragma unroll
                for (int j = 0; j < 4; ++j)
                    acc[i][j] = fmaf(ha[i], wa[j], acc[i][j]);
        }
        __syncthreads();
    }
#pragma unroll
    for (int i = 0; i < 4; ++i) {
#pragma unroll
        for (int j = 0; j < 4; ++j) {
            int oo = o0 + tx * 4 + j;
            ys[(size_t)(t0 + ty * 4 + i) * OUTW + oo] = acc[i][j] + by[oo];
        }
    }
}

extern "C" void kernel_launch(void* const* d_in, const int* in_sizes, int n_in,
                              void* d_out, int out_size, void* d_ws, size_t ws_size,
                              hipStream_t stream) {
    const float* x   = (const float*)d_in[0];
    const float* wf  = (const float*)d_in[1];
    const float* bf  = (const float*)d_in[2];
    const float* wi  = (const float*)d_in[3];
    const float* bi  = (const float*)d_in[4];
    const float* wc  = (const float*)d_in[5];
    const float* bc  = (const float*)d_in[6];
    const float* wo  = (const float*)d_in[7];
    const float* bo  = (const float*)d_in[8];
    const float* why = (const float*)d_in[9];
    const float* by  = (const float*)d_in[10];
    float* out = (float*)d_out;

    uint64_t* hpair = (uint64_t*)d_ws;
    float* h_all = (float*)((char*)d_ws + (size_t)2 * HW * sizeof(uint64_t));

    lstm_init_kernel<<<dim3(4), dim3(256), 0, stream>>>(hpair);
    lstm_seq_kernel<<<dim3(256), dim3(256), 0, stream>>>(
        x, wf, bf, wi, bi, wc, bc, wo, bo, hpair, h_all, out);
    lstm_ygemm_kernel<<<dim3(64, 8), dim3(256), 0, stream>>>(h_all, why, by, out);
}

// Round 3
// 13643.390 us; speedup vs baseline: 1.1019x; 1.0162x over previous
//
#include <hip/hip_runtime.h>
#include <stdint.h>

#define TT 4096
#define INW 1024
#define HW 1024
#define OUTW 512
#define CH 2048  // HW+INW

// ws layout:
//   [0, 16KB)           : hpair[2][1024]  (uint64: epoch<<32 | float_bits)
//   [16KB, 16KB+16MB)   : h_all float[TT*HW]

__device__ __forceinline__ uint64_t pack_pair(float v, uint32_t ep) {
    return ((uint64_t)ep << 32) | (uint64_t)__float_as_uint(v);
}

__device__ __forceinline__ float sigmoid_fast(float z) {
    return 1.0f / (1.0f + __expf(-z));
}
__device__ __forceinline__ float tanh_fast(float z) {
    // exact at saturation: z>>0 -> 1 ; z<<0 -> -1
    return 1.0f - 2.0f / (1.0f + __expf(2.0f * z));
}

__global__ void lstm_init_kernel(uint64_t* __restrict__ hpair) {
    int j = blockIdx.x * blockDim.x + threadIdx.x;
    if (j < HW) {
        hpair[j]      = pack_pair(0.0f, 0u);          // buf0: h_0 = 0, epoch 0
        hpair[HW + j] = pack_pair(0.0f, 0x80000000u); // buf1: never-matching epoch
    }
}

// 256 blocks x 256 threads. Block b owns hidden units 4b..4b+3.
// Wave w owns unit gu = 4b+w (all four gates f,i,c~,o).
// Lane l covers concat columns {l + 64k : k=0..31}; k<16 -> h part, k>=16 -> x part.
// launch_bounds(256,1): 512-VGPR cap. We FORCE the 128 weight floats to stay
// in VGPRs (see asm fence below); (256,2)'s 256-reg cap would spill.
__global__ __launch_bounds__(256, 1) void lstm_seq_kernel(
    const float* __restrict__ x,
    const float* __restrict__ wf, const float* __restrict__ bf,
    const float* __restrict__ wi, const float* __restrict__ bi,
    const float* __restrict__ wc, const float* __restrict__ bc,
    const float* __restrict__ wo, const float* __restrict__ bo,
    uint64_t* __restrict__ hpair, float* __restrict__ h_all,
    float* __restrict__ out)
{
    __shared__ float hsh[HW];  // 4KB: h_t shared within block

    const int tid  = threadIdx.x;
    const int lane = tid & 63;
    const int w    = tid >> 6;            // wave 0..3
    const int b    = blockIdx.x;          // 0..255
    const int gu   = b * 4 + w;           // global hidden unit owned by this wave

    // ---- one-time: load weights into registers (coalesced: lane-stride 4B) ----
    float wreg[128];  // wreg[j*32+k] = W_j[gu*2048 + lane + 64k]
    {
        const float* wptr[4] = {wf, wi, wc, wo};
#pragma unroll
        for (int j = 0; j < 4; ++j) {
            const float* base = wptr[j] + (size_t)gu * CH + lane;
#pragma unroll
            for (int k = 0; k < 32; ++k) {
                wreg[j * 32 + k] = base[(size_t)k * 64];
            }
        }
    }
    // Opaque redefinition: the asm becomes the producer of each weight value,
    // so the compiler CANNOT re-materialize the global loads inside the t-loop
    // (R2 forensics: VGPR_Count=112 < 128 => weights were being re-streamed
    // from L2/L3 every step, ~32MB/step device-wide ~ 9ms of the 14ms).
#pragma unroll
    for (int i = 0; i < 128; ++i)
        asm volatile("" : "+v"(wreg[i]));

    const float bias0 = bf[gu];
    const float bias1 = bi[gu];
    const float bias2 = bc[gu];
    const float bias3 = bo[gu];

    float c = 0.0f;       // cell state (meaningful on lane 0)
    float h_last = 0.0f;  // last hidden (meaningful on lane 0)

    for (int t = 0; t < TT; ++t) {
        float acc0 = 0.0f, acc1 = 0.0f, acc2 = 0.0f, acc3 = 0.0f;

        // ---- x part (independent of recurrence; overlaps the h wait) ----
        const float* xt = x + (size_t)t * INW + lane;
#pragma unroll
        for (int k = 0; k < 16; ++k) {
            float xv = xt[(size_t)k * 64];
            acc0 = fmaf(wreg[0 * 32 + 16 + k], xv, acc0);
            acc1 = fmaf(wreg[1 * 32 + 16 + k], xv, acc1);
            acc2 = fmaf(wreg[2 * 32 + 16 + k], xv, acc2);
            acc3 = fmaf(wreg[3 * 32 + 16 + k], xv, acc3);
        }

        // ---- wave 0 polls the fused (epoch,value) pairs for h_t ----
        // SYSTEM-scope loads: bypass L1+L2, read the device coherence point.
        const uint64_t* hp = hpair + (size_t)(t & 1) * HW;
        if (w == 0) {
            float hv[16];
            bool ok;
            do {
                uint64_t pv[16];
#pragma unroll
                for (int k = 0; k < 16; ++k)
                    pv[k] = __hip_atomic_load(&hp[lane + 64 * k],
                                              __ATOMIC_RELAXED, __HIP_MEMORY_SCOPE_SYSTEM);
                ok = true;
#pragma unroll
                for (int k = 0; k < 16; ++k)
                    ok &= ((uint32_t)(pv[k] >> 32) == (uint32_t)t);
#pragma unroll
                for (int k = 0; k < 16; ++k)
                    hv[k] = __uint_as_float((uint32_t)pv[k]);
            } while (!__all(ok));
#pragma unroll
            for (int k = 0; k < 16; ++k)
                hsh[lane + 64 * k] = hv[k];  // bank-conflict-free (stride 64)
        }
        __syncthreads();

        // ---- h part ----
#pragma unroll
        for (int k = 0; k < 16; ++k) {
            float hv = hsh[lane + 64 * k];
            acc0 = fmaf(wreg[0 * 32 + k], hv, acc0);
            acc1 = fmaf(wreg[1 * 32 + k], hv, acc1);
            acc2 = fmaf(wreg[2 * 32 + k], hv, acc2);
            acc3 = fmaf(wreg[3 * 32 + k], hv, acc3);
        }
        // NOTE: no second __syncthreads needed: wave0 can only rewrite hsh (next
        // iter) after observing ALL blocks' h_{t+1}, which requires this block's
        // waves 1..3 to have published, i.e. to be past their hsh reads.

        // ---- 64-lane reduction per gate ----
#pragma unroll
        for (int s = 32; s > 0; s >>= 1) {
            acc0 += __shfl_xor(acc0, s, 64);
            acc1 += __shfl_xor(acc1, s, 64);
            acc2 += __shfl_xor(acc2, s, 64);
            acc3 += __shfl_xor(acc3, s, 64);
        }

        if (lane == 0) {
            float f  = sigmoid_fast(acc0 + bias0);
            float ii = sigmoid_fast(acc1 + bias1);
            float g  = tanh_fast(acc2 + bias2);
            float o  = sigmoid_fast(acc3 + bias3);
            c = fmaf(f, c, ii * g);
            float hn = o * tanh_fast(c);
            // Publish FIRST (memory-side RMW: lands at the coherence point
            // immediately, never lingers dirty in this XCD's L2).
            (void)__hip_atomic_exchange(
                &hpair[(size_t)((t + 1) & 1) * HW + gu],
                pack_pair(hn, (uint32_t)(t + 1)),
                __ATOMIC_RELAXED, __HIP_MEMORY_SCOPE_AGENT);
            h_last = hn;
            h_all[(size_t)t * HW + gu] = hn;  // for the ys GEMM (read next kernel)
        }
    }

    // ---- final h, c outputs ----
    if (lane == 0) {
        out[(size_t)TT * OUTW + gu]      = h_last;
        out[(size_t)TT * OUTW + HW + gu] = c;
    }
}

// ys[t][o] = sum_k h_all[t][k] * why[o][k] + by[o]
// grid (TT/64, OUTW/64) = (64, 8); block 256; 64x64 tile, 4x4 per thread.
__global__ __launch_bounds__(256) void lstm_ygemm_kernel(
    const float* __restrict__ hall, const float* __restrict__ why,
    const float* __restrict__ by, float* __restrict__ ys)
{
    __shared__ float hs[64][17];
    __shared__ float wsm[64][17];
    const int t0 = blockIdx.x * 64, o0 = blockIdx.y * 64;
    const int tid = threadIdx.x;
    const int tx = tid & 15, ty = tid >> 4;

    float acc[4][4] = {};
    const int r = tid >> 2;            // 0..63
    const int cc = (tid & 3) * 4;      // 0,4,8,12

    for (int kk = 0; kk < HW; kk += 16) {
        float4 hv = *(const float4*)(hall + (size_t)(t0 + r) * HW + kk + cc);
        hs[r][cc + 0] = hv.x; hs[r][cc + 1] = hv.y;
        hs[r][cc + 2] = hv.z; hs[r][cc + 3] = hv.w;
        float4 wv = *(const float4*)(why + (size_t)(o0 + r) * HW + kk + cc);
        wsm[r][cc + 0] = wv.x; wsm[r][cc + 1] = wv.y;
        wsm[r][cc + 2] = wv.z; wsm[r][cc + 3] = wv.w;
        __syncthreads();
#pragma unroll
        for (int k = 0; k < 16; ++k) {
            float ha[4], wa[4];
#pragma unroll
            for (int i = 0; i < 4; ++i) ha[i] = hs[ty * 4 + i][k];
#pragma unroll
            for (int j = 0; j < 4; ++j) wa[j] = wsm[tx * 4 + j][k];
#pragma unroll
            for (int i = 0; i < 4; ++i)
#pragma unroll
                for (int j = 0; j < 4; ++j)
                    acc[i][j] = fmaf(ha[i], wa[j], acc[i][j]);
        }
        __syncthreads();
    }
#pragma unroll
    for (int i = 0; i < 4; ++i) {
#pragma unroll
        for (int j = 0; j < 4; ++j) {
            int oo = o0 + tx * 4 + j;
            ys[(size_t)(t0 + ty * 4 + i) * OUTW + oo] = acc[i][j] + by[oo];
        }
    }
}

extern "C" void kernel_launch(void* const* d_in, const int* in_sizes, int n_in,
                              void* d_out, int out_size, void* d_ws, size_t ws_size,
                              hipStream_t stream) {
    const float* x   = (const float*)d_in[0];
    const float* wf  = (const float*)d_in[1];
    const float* bf  = (const float*)d_in[2];
    const float* wi  = (const float*)d_in[3];
    const float* bi  = (const float*)d_in[4];
    const float* wc  = (const float*)d_in[5];
    const float* bc  = (const float*)d_in[6];
    const float* wo  = (const float*)d_in[7];
    const float* bo  = (const float*)d_in[8];
    const float* why = (const float*)d_in[9];
    const float* by  = (const float*)d_in[10];
    float* out = (float*)d_out;

    uint64_t* hpair = (uint64_t*)d_ws;
    float* h_all = (float*)((char*)d_ws + (size_t)2 * HW * sizeof(uint64_t));

    lstm_init_kernel<<<dim3(4), dim3(256), 0, stream>>>(hpair);
    lstm_seq_kernel<<<dim3(256), dim3(256), 0, stream>>>(
        x, wf, bf, wi, bi, wc, bc, wo, bo, hpair, h_all, out);
    lstm_ygemm_kernel<<<dim3(64, 8), dim3(256), 0, stream>>>(h_all, why, by, out);
}

// Round 5
// 7828.813 us; speedup vs baseline: 1.9202x; 1.7427x over previous
//
#include <hip/hip_runtime.h>
#include <stdint.h>

#define TT 4096
#define INW 1024
#define HW 1024
#define OUTW 512
#define CH 2048  // HW+IN

// ws layout:
//   [0, 16KB)           : hpair[2][1024]  (uint64: epoch<<32 | float_bits)
//   [16KB, 16KB+16MB)   : h_all float[TT*HW]

__device__ __forceinline__ uint64_t pack_pair(float v, uint32_t ep) {
    return ((uint64_t)ep << 32) | (uint64_t)__float_as_uint(v);
}
__device__ __forceinline__ float sigmoid_fast(float z) {
    return 1.0f / (1.0f + __expf(-z));
}
__device__ __forceinline__ float tanh_fast(float z) {
    return 1.0f - 2.0f / (1.0f + __expf(2.0f * z));
}

__global__ void lstm_init_kernel(uint64_t* __restrict__ hpair) {
    int j = blockIdx.x * blockDim.x + threadIdx.x;
    if (j < HW) {
        hpair[j]      = pack_pair(0.0f, 0u);          // buf0: h_0 = 0, epoch 0
        hpair[HW + j] = pack_pair(0.0f, 0x80000000u); // buf1: never-matching epoch
    }
}

// 256 blocks x 256 threads. Block b owns hidden units 4b..4b+3; wave w owns
// unit gu=4b+w (all 4 gates). Lane l covers concat columns {l+64k}.
// Handoff: wave w polls pair-quarter [256w,256w+256) (4 loads/lane) straight
// into registers, shares via double-buffered LDS with ONE barrier/step.
__global__ __launch_bounds__(256, 1) void lstm_seq_kernel(
    const float* __restrict__ x,
    const float* __restrict__ wf, const float* __restrict__ bf,
    const float* __restrict__ wi, const float* __restrict__ bi,
    const float* __restrict__ wc, const float* __restrict__ bc,
    const float* __restrict__ wo, const float* __restrict__ bo,
    uint64_t* __restrict__ hpair, float* __restrict__ h_all,
    float* __restrict__ out)
{
    __shared__ float hsh[2][HW];  // 8KB double-buffered h state

    const int tid  = threadIdx.x;
    const int lane = tid & 63;
    const int w    = tid >> 6;            // wave 0..3
    const int b    = blockIdx.x;          // 0..255
    const int gu   = b * 4 + w;           // owned hidden unit

    // ---- one-time: weights into registers (coalesced) ----
    float wh[64], wx[64];  // wh[g*16+k] = W_g[gu][lane+64k]; wx: +1024
    {
        const float* wptr[4] = {wf, wi, wc, wo};
#pragma unroll
        for (int g = 0; g < 4; ++g) {
            const float* base = wptr[g] + (size_t)gu * CH + lane;
#pragma unroll
            for (int k = 0; k < 16; ++k) wh[g * 16 + k] = base[(size_t)k * 64];
#pragma unroll
            for (int k = 0; k < 16; ++k) wx[g * 16 + k] = base[1024 + (size_t)k * 64];
        }
    }
    // Keep resident on-chip, never re-streamed in the loop.
#pragma unroll
    for (int i = 0; i < 64; ++i) {
        asm volatile("" : "+v"(wh[i]));
        asm volatile("" : "+v"(wx[i]));
    }

    const float bias0 = bf[gu];
    const float bias1 = bi[gu];
    const float bias2 = bc[gu];
    const float bias3 = bo[gu];

    // x_0 preload (subsequent rows are prefetched inside the loop)
    float xv[16];
    {
        const float* xp = x + lane;
#pragma unroll
        for (int k = 0; k < 16; ++k) xv[k] = xp[(size_t)k * 64];
    }

    float c = 0.0f, h_last = 0.0f;  // maintained identically on ALL lanes

    for (int t = 0; t < TT; ++t) {
        float acc0 = 0.f, acc1 = 0.f, acc2 = 0.f, acc3 = 0.f;

        // ---- x part: register-resident inputs, no memory wait ----
#pragma unroll
        for (int k = 0; k < 16; ++k) {
            float v = xv[k];
            acc0 = fmaf(wx[0 * 16 + k], v, acc0);
            acc1 = fmaf(wx[1 * 16 + k], v, acc1);
            acc2 = fmaf(wx[2 * 16 + k], v, acc2);
            acc3 = fmaf(wx[3 * 16 + k], v, acc3);
        }

        // ---- poll my quarter (SYSTEM scope: read the coherence point) ----
        const uint64_t* hp = hpair + (size_t)(t & 1) * HW + 256 * w + lane;
        float hq[4];
        {
            bool ok;
            do {
                uint64_t pv[4];
#pragma unroll
                for (int k = 0; k < 4; ++k)
                    pv[k] = __hip_atomic_load(&hp[64 * k],
                                              __ATOMIC_RELAXED, __HIP_MEMORY_SCOPE_SYSTEM);
                ok = true;
#pragma unroll
                for (int k = 0; k < 4; ++k)
                    ok &= ((uint32_t)(pv[k] >> 32) == (uint32_t)t);
#pragma unroll
                for (int k = 0; k < 4; ++k)
                    hq[k] = __uint_as_float((uint32_t)pv[k]);
            } while (!__all(ok));
        }

        // ---- prefetch x_{t+1}: issues now, completes under the h phase ----
        float xn[16];
        {
            const float* xp = x + (size_t)(t + 1 < TT ? t + 1 : t) * INW + lane;
#pragma unroll
            for (int k = 0; k < 16; ++k) xn[k] = xp[(size_t)k * 64];
        }

        // ---- share quarters via LDS; single barrier per step ----
#pragma unroll
        for (int k = 0; k < 4; ++k)
            hsh[t & 1][256 * w + lane + 64 * k] = hq[k];
        __syncthreads();
        // (no 2nd barrier: hsh[t&1] is next written at t+2; passing the poll
        //  for epoch t+2 implies every block passed step t+1's barrier, which
        //  is after all step-t reads of hsh[t&1]. Double-buffer + induction.)

        // ---- coalesced h_all write: hsh[t&1] = state ENTERING step t
        //      = h produced by step t-1  ->  row t-1.  (R4 bug: wrote row t.)
        if (t >= 1 && b == (t & 255)) {
            float4 hv4 = *(const float4*)&hsh[t & 1][tid * 4];
            *(float4*)(h_all + (size_t)(t - 1) * HW + tid * 4) = hv4;
        }

        // ---- h part ----
#pragma unroll
        for (int k = 0; k < 16; ++k) {
            float v = hsh[t & 1][lane + 64 * k];
            acc0 = fmaf(wh[0 * 16 + k], v, acc0);
            acc1 = fmaf(wh[1 * 16 + k], v, acc1);
            acc2 = fmaf(wh[2 * 16 + k], v, acc2);
            acc3 = fmaf(wh[3 * 16 + k], v, acc3);
        }

        // ---- 64-lane butterfly: full sums land on every lane ----
#pragma unroll
        for (int s = 32; s > 0; s >>= 1) {
            acc0 += __shfl_xor(acc0, s, 64);
            acc1 += __shfl_xor(acc1, s, 64);
            acc2 += __shfl_xor(acc2, s, 64);
            acc3 += __shfl_xor(acc3, s, 64);
        }

        // ---- activations (all lanes, identical -> c/h stay coherent) ----
        float f  = sigmoid_fast(acc0 + bias0);
        float ii = sigmoid_fast(acc1 + bias1);
        float g  = tanh_fast(acc2 + bias2);
        float o  = sigmoid_fast(acc3 + bias3);
        c = fmaf(f, c, ii * g);
        float hn = o * tanh_fast(c);
        h_last = hn;

        if (lane == 0) {
            // write-through publish: value+epoch fused in one 8B store
            __hip_atomic_store(&hpair[(size_t)((t + 1) & 1) * HW + gu],
                               pack_pair(hn, (uint32_t)(t + 1)),
                               __ATOMIC_RELAXED, __HIP_MEMORY_SCOPE_SYSTEM);
        }

#pragma unroll
        for (int k = 0; k < 16; ++k) xv[k] = xn[k];
    }

    if (lane == 0) {
        // final h_all row (epoch TT is never polled by anyone)
        h_all[(size_t)(TT - 1) * HW + gu] = h_last;
        out[(size_t)TT * OUTW + gu]      = h_last;
        out[(size_t)TT * OUTW + HW + gu] = c;
    }
}

// ys[t][o] = sum_k h_all[t][k] * why[o][k] + by[o]
// grid (TT/64, OUTW/64) = (64, 8); block 256; 64x64 tile, 4x4 per thread.
__global__ __launch_bounds__(256) void lstm_ygemm_kernel(
    const float* __restrict__ hall, const float* __restrict__ why,
    const float* __restrict__ by, float* __restrict__ ys)
{
    __shared__ float hs[64][17];
    __shared__ float wsm[64][17];
    const int t0 = blockIdx.x * 64, o0 = blockIdx.y * 64;
    const int tid = threadIdx.x;
    const int tx = tid & 15, ty = tid >> 4;

    float acc[4][4] = {};
    const int r = tid >> 2;            // 0..63
    const int cc = (tid & 3) * 4;      // 0,4,8,12

    for (int kk = 0; kk < HW; kk += 16) {
        float4 hv = *(const float4*)(hall + (size_t)(t0 + r) * HW + kk + cc);
        hs[r][cc + 0] = hv.x; hs[r][cc + 1] = hv.y;
        hs[r][cc + 2] = hv.z; hs[r][cc + 3] = hv.w;
        float4 wv = *(const float4*)(why + (size_t)(o0 + r) * HW + kk + cc);
        wsm[r][cc + 0] = wv.x; wsm[r][cc + 1] = wv.y;
        wsm[r][cc + 2] = wv.z; wsm[r][cc + 3] = wv.w;
        __syncthreads();
#pragma unroll
        for (int k = 0; k < 16; ++k) {
            float ha[4], wa[4];
#pragma unroll
            for (int i = 0; i < 4; ++i) ha[i] = hs[ty * 4 + i][k];
#pragma unroll
            for (int j = 0; j < 4; ++j) wa[j] = wsm[tx * 4 + j][k];
#pragma unroll
            for (int i = 0; i < 4; ++i)
#pragma unroll
                for (int j = 0; j < 4; ++j)
                    acc[i][j] = fmaf(ha[i], wa[j], acc[i][j]);
        }
        __syncthreads();
    }
#pragma unroll
    for (int i = 0; i < 4; ++i) {
#pragma unroll
        for (int j = 0; j < 4; ++j) {
            int oo = o0 + tx * 4 + j;
            ys[(size_t)(t0 + ty * 4 + i) * OUTW + oo] = acc[i][j] + by[oo];
        }
    }
}

extern "C" void kernel_launch(void* const* d_in, const int* in_sizes, int n_in,
                              void* d_out, int out_size, void* d_ws, size_t ws_size,
                              hipStream_t stream) {
    const float* x   = (const float*)d_in[0];
    const float* wf  = (const float*)d_in[1];
    const float* bf  = (const float*)d_in[2];
    const float* wi  = (const float*)d_in[3];
    const float* bi  = (const float*)d_in[4];
    const float* wc  = (const float*)d_in[5];
    const float* bc  = (const float*)d_in[6];
    const float* wo  = (const float*)d_in[7];
    const float* bo  = (const float*)d_in[8];
    const float* why = (const float*)d_in[9];
    const float* by  = (const float*)d_in[10];
    float* out = (float*)d_out;

    uint64_t* hpair = (uint64_t*)d_ws;
    float* h_all = (float*)((char*)d_ws + (size_t)2 * HW * sizeof(uint64_t));

    lstm_init_kernel<<<dim3(4), dim3(256), 0, stream>>>(hpair);
    lstm_seq_kernel<<<dim3(256), dim3(256), 0, stream>>>(
        x, wf, bf, wi, bi, wc, bc, wo, bo, hpair, h_all, out);
    lstm_ygemm_kernel<<<dim3(64, 8), dim3(256), 0, stream>>>(h_all, why, by, out);
}

// Round 6
// 6757.114 us; speedup vs baseline: 2.2248x; 1.1586x over previous
//
#include <hip/hip_runtime.h>
#include <stdint.h>

#define TT 4096
#define INW 1024
#define HW 1024
#define OUTW 512
#define CH 2048  // HW+IN

// ws layout:
//   [0, 16KB)           : hpair[2][1024]  (uint64: epoch<<32 | float_bits)
//   [16KB, 16KB+16MB)   : h_all float[TT*HW]

__device__ __forceinline__ uint64_t pack_pair(float v, uint32_t ep) {
    return ((uint64_t)ep << 32) | (uint64_t)__float_as_uint(v);
}
__device__ __forceinline__ float sigmoid_fast(float z) {
    return 1.0f / (1.0f + __expf(-z));
}
__device__ __forceinline__ float tanh_fast(float z) {
    return 1.0f - 2.0f / (1.0f + __expf(2.0f * z));
}

// DPP wave64 sum: result lands in lane 63 (other lanes hold partials).
template <int CTRL>
__device__ __forceinline__ float dpp_add(float v) {
    int s = __builtin_amdgcn_update_dpp(0, __float_as_int(v), CTRL, 0xF, 0xF, true);
    return v + __int_as_float(s);
}
__device__ __forceinline__ float wave_sum_to_lane63(float v) {
    v = dpp_add<0x111>(v);  // row_shr:1
    v = dpp_add<0x112>(v);  // row_shr:2
    v = dpp_add<0x114>(v);  // row_shr:4
    v = dpp_add<0x118>(v);  // row_shr:8  -> lane 15/31/47/63 = row sums
    v = dpp_add<0x142>(v);  // row_bcast:15
    v = dpp_add<0x143>(v);  // row_bcast:31 -> lane 63 = total
    return v;
}

__global__ void lstm_init_kernel(uint64_t* __restrict__ hpair) {
    int j = blockIdx.x * blockDim.x + threadIdx.x;
    if (j < HW) {
        hpair[j]      = pack_pair(0.0f, 0u);          // buf0: h_0 = 0, epoch 0
        hpair[HW + j] = pack_pair(0.0f, 0x80000000u); // buf1: never-matching epoch
    }
}

// 256 blocks x 256 threads. Block b owns hidden units 4b..4b+3; wave w owns
// unit gu=4b+w (all 4 gates). Lane l covers concat columns {l+64k}.
// Wave w polls pair-quarter [256w,256w+256) (4 loads/lane), shares via
// double-buffered LDS + ONE barrier. x-matvec is pipelined off the critical
// path: xacc for step t+1 is computed AFTER publishing epoch t+1.
__global__ __launch_bounds__(256, 1) void lstm_seq_kernel(
    const float* __restrict__ x,
    const float* __restrict__ wf, const float* __restrict__ bf,
    const float* __restrict__ wi, const float* __restrict__ bi,
    const float* __restrict__ wc, const float* __restrict__ bc,
    const float* __restrict__ wo, const float* __restrict__ bo,
    uint64_t* __restrict__ hpair, float* __restrict__ h_all,
    float* __restrict__ out)
{
    __shared__ float hsh[2][HW];  // 8KB double-buffered h state

    const int tid  = threadIdx.x;
    const int lane = tid & 63;
    const int w    = tid >> 6;            // wave 0..3
    const int b    = blockIdx.x;          // 0..255
    const int gu   = b * 4 + w;           // owned hidden unit

    // ---- one-time: weights into registers (coalesced) ----
    float wh[64], wx[64];  // wh[g*16+k] = W_g[gu][lane+64k]; wx: +1024
    {
        const float* wptr[4] = {wf, wi, wc, wo};
#pragma unroll
        for (int g = 0; g < 4; ++g) {
            const float* base = wptr[g] + (size_t)gu * CH + lane;
#pragma unroll
            for (int k = 0; k < 16; ++k) wh[g * 16 + k] = base[(size_t)k * 64];
#pragma unroll
            for (int k = 0; k < 16; ++k) wx[g * 16 + k] = base[1024 + (size_t)k * 64];
        }
    }
#pragma unroll
    for (int i = 0; i < 64; ++i) {
        asm volatile("" : "+v"(wh[i]));
        asm volatile("" : "+v"(wx[i]));
    }

    const float bias0 = bf[gu];
    const float bias1 = bi[gu];
    const float bias2 = bc[gu];
    const float bias3 = bo[gu];

    // ---- prologue: x_0 load + its partial sums ----
    float xacc0 = 0.f, xacc1 = 0.f, xacc2 = 0.f, xacc3 = 0.f;
    {
        const float* xp = x + lane;
        float xv[16];
#pragma unroll
        for (int k = 0; k < 16; ++k) xv[k] = xp[(size_t)k * 64];
#pragma unroll
        for (int k = 0; k < 16; ++k) {
            xacc0 = fmaf(wx[0 * 16 + k], xv[k], xacc0);
            xacc1 = fmaf(wx[1 * 16 + k], xv[k], xacc1);
            xacc2 = fmaf(wx[2 * 16 + k], xv[k], xacc2);
            xacc3 = fmaf(wx[3 * 16 + k], xv[k], xacc3);
        }
    }

    float c = 0.0f, h_last = 0.0f;  // meaningful on lane 63

    for (int t = 0; t < TT; ++t) {
        const int p = t & 1;

        // ---- 1. poll my quarter (SYSTEM scope: read the coherence point) ----
        const uint64_t* hp = hpair + (size_t)p * HW + 256 * w + lane;
        float hq[4];
        {
            bool ok;
            do {
                uint64_t pv[4];
#pragma unroll
                for (int k = 0; k < 4; ++k)
                    pv[k] = __hip_atomic_load(&hp[64 * k],
                                              __ATOMIC_RELAXED, __HIP_MEMORY_SCOPE_SYSTEM);
                ok = true;
#pragma unroll
                for (int k = 0; k < 4; ++k)
                    ok &= ((uint32_t)(pv[k] >> 32) == (uint32_t)t);
#pragma unroll
                for (int k = 0; k < 4; ++k)
                    hq[k] = __uint_as_float((uint32_t)pv[k]);
            } while (!__all(ok));
        }

        // ---- 2. share quarters via LDS; single barrier per step ----
#pragma unroll
        for (int k = 0; k < 4; ++k)
            hsh[p][256 * w + lane + 64 * k] = hq[k];
        __syncthreads();
        // (no 2nd barrier: hsh[p] is next written at t+2; passing the poll for
        //  epoch t+2 implies every block passed step t+1, which is after all
        //  step-t reads of hsh[p]. Double-buffer + induction.)

        // ---- 3. prefetch x_{t+1} AFTER the barrier (so the barrier's
        //         vmcnt(0) drain does NOT wait on it; consumed post-publish) --
        float xn[16];
        {
            const int tn = (t + 1 < TT) ? t + 1 : t;
            const float* xp = x + (size_t)tn * INW + lane;
#pragma unroll
            for (int k = 0; k < 16; ++k) xn[k] = xp[(size_t)k * 64];
        }

        // ---- 4. coalesced h_all write: hsh[p] = state entering step t
        //         = h produced by step t-1 -> row t-1 ----
        if (t >= 1 && b == (t & 255)) {
            float4 hv4 = *(const float4*)&hsh[p][tid * 4];
            *(float4*)(h_all + (size_t)(t - 1) * HW + tid * 4) = hv4;
        }

        // ---- 5. h part (starts from the pipelined x partial sums) ----
        float acc0 = xacc0, acc1 = xacc1, acc2 = xacc2, acc3 = xacc3;
#pragma unroll
        for (int k = 0; k < 16; ++k) {
            float v = hsh[p][lane + 64 * k];
            acc0 = fmaf(wh[0 * 16 + k], v, acc0);
            acc1 = fmaf(wh[1 * 16 + k], v, acc1);
            acc2 = fmaf(wh[2 * 16 + k], v, acc2);
            acc3 = fmaf(wh[3 * 16 + k], v, acc3);
        }

        // ---- 6. DPP reduce: full sums land in lane 63 (VALU pipe, no LDS) --
        acc0 = wave_sum_to_lane63(acc0);
        acc1 = wave_sum_to_lane63(acc1);
        acc2 = wave_sum_to_lane63(acc2);
        acc3 = wave_sum_to_lane63(acc3);

        // ---- 7. lane 63: activations + publish epoch t+1 ----
        if (lane == 63) {
            float f  = sigmoid_fast(acc0 + bias0);
            float ii = sigmoid_fast(acc1 + bias1);
            float g  = tanh_fast(acc2 + bias2);
            float o  = sigmoid_fast(acc3 + bias3);
            c = fmaf(f, c, ii * g);
            float hn = o * tanh_fast(c);
            h_last = hn;
            __hip_atomic_store(&hpair[(size_t)((t + 1) & 1) * HW + gu],
                               pack_pair(hn, (uint32_t)(t + 1)),
                               __ATOMIC_RELAXED, __HIP_MEMORY_SCOPE_SYSTEM);
        }
        __builtin_amdgcn_sched_barrier(0);  // keep xacc recompute below the publish

        // ---- 8. post-publish (off critical path): x partials for t+1 ----
        float nx0 = 0.f, nx1 = 0.f, nx2 = 0.f, nx3 = 0.f;
#pragma unroll
        for (int k = 0; k < 16; ++k) {
            nx0 = fmaf(wx[0 * 16 + k], xn[k], nx0);
            nx1 = fmaf(wx[1 * 16 + k], xn[k], nx1);
            nx2 = fmaf(wx[2 * 16 + k], xn[k], nx2);
            nx3 = fmaf(wx[3 * 16 + k], xn[k], nx3);
        }
        xacc0 = nx0; xacc1 = nx1; xacc2 = nx2; xacc3 = nx3;
    }

    if (lane == 63) {
        // final h_all row (epoch TT is never polled by anyone)
        h_all[(size_t)(TT - 1) * HW + gu] = h_last;
        out[(size_t)TT * OUTW + gu]      = h_last;
        out[(size_t)TT * OUTW + HW + gu] = c;
    }
}

// ys[t][o] = sum_k h_all[t][k] * why[o][k] + by[o]
// grid (TT/64, OUTW/64) = (64, 8); block 256; 64x64 tile, 4x4 per thread.
__global__ __launch_bounds__(256) void lstm_ygemm_kernel(
    const float* __restrict__ hall, const float* __restrict__ why,
    const float* __restrict__ by, float* __restrict__ ys)
{
    __shared__ float hs[64][17];
    __shared__ float wsm[64][17];
    const int t0 = blockIdx.x * 64, o0 = blockIdx.y * 64;
    const int tid = threadIdx.x;
    const int tx = tid & 15, ty = tid >> 4;

    float acc[4][4] = {};
    const int r = tid >> 2;            // 0..63
    const int cc = (tid & 3) * 4;      // 0,4,8,12

    for (int kk = 0; kk < HW; kk += 16) {
        float4 hv = *(const float4*)(hall + (size_t)(t0 + r) * HW + kk + cc);
        hs[r][cc + 0] = hv.x; hs[r][cc + 1] = hv.y;
        hs[r][cc + 2] = hv.z; hs[r][cc + 3] = hv.w;
        float4 wv = *(const float4*)(why + (size_t)(o0 + r) * HW + kk + cc);
        wsm[r][cc + 0] = wv.x; wsm[r][cc + 1] = wv.y;
        wsm[r][cc + 2] = wv.z; wsm[r][cc + 3] = wv.w;
        __syncthreads();
#pragma unroll
        for (int k = 0; k < 16; ++k) {
            float ha[4], wa[4];
#pragma unroll
            for (int i = 0; i < 4; ++i) ha[i] = hs[ty * 4 + i][k];
#pragma unroll
            for (int j = 0; j < 4; ++j) wa[j] = wsm[tx * 4 + j][k];
#pragma unroll
            for (int i = 0; i < 4; ++i)
#pragma unroll
                for (int j = 0; j < 4; ++j)
                    acc[i][j] = fmaf(ha[i], wa[j], acc[i][j]);
        }
        __syncthreads();
    }
#pragma unroll
    for (int i = 0; i < 4; ++i) {
#pragma unroll
        for (int j = 0; j < 4; ++j) {
            int oo = o0 + tx * 4 + j;
            ys[(size_t)(t0 + ty * 4 + i) * OUTW + oo] = acc[i][j] + by[oo];
        }
    }
}

extern "C" void kernel_launch(void* const* d_in, const int* in_sizes, int n_in,
                              void* d_out, int out_size, void* d_ws, size_t ws_size,
                              hipStream_t stream) {
    const float* x   = (const float*)d_in[0];
    const float* wf  = (const float*)d_in[1];
    const float* bf  = (const float*)d_in[2];
    const float* wi  = (const float*)d_in[3];
    const float* bi  = (const float*)d_in[4];
    const float* wc  = (const float*)d_in[5];
    const float* bc  = (const float*)d_in[6];
    const float* wo  = (const float*)d_in[7];
    const float* bo  = (const float*)d_in[8];
    const float* why = (const float*)d_in[9];
    const float* by  = (const float*)d_in[10];
    float* out = (float*)d_out;

    uint64_t* hpair = (uint64_t*)d_ws;
    float* h_all = (float*)((char*)d_ws + (size_t)2 * HW * sizeof(uint64_t));

    lstm_init_kernel<<<dim3(4), dim3(256), 0, stream>>>(hpair);
    lstm_seq_kernel<<<dim3(256), dim3(256), 0, stream>>>(
        x, wf, bf, wi, bi, wc, bc, wo, bo, hpair, h_all, out);
    lstm_ygemm_kernel<<<dim3(64, 8), dim3(256), 0, stream>>>(h_all, why, by, out);
}